// Round 1
// baseline (1150.087 us; speedup 1.0000x reference)
//
#include <hip/hip_runtime.h>

#define N_NODES 100000
#define N_EDGES 1600000
#define IN_CH 50
#define HID_CH 32
#define OUT_CH 16
#define EPSN 1e-12f

// ---------------- Layer-1 node transform: xl = x@W1l.T, self1 = x@W1r.T + b1l
__global__ __launch_bounds__(256) void k_xform1(
    const float* __restrict__ x, const float* __restrict__ W1l,
    const float* __restrict__ b1l, const float* __restrict__ W1r,
    float* __restrict__ xl, float* __restrict__ self1)
{
    int n = blockIdx.x * blockDim.x + threadIdx.x;
    if (n >= N_NODES) return;
    float row[IN_CH];
    #pragma unroll
    for (int k = 0; k < IN_CH; ++k) row[k] = x[(size_t)n * IN_CH + k];
    #pragma unroll 4
    for (int c = 0; c < HID_CH; ++c) {
        float aL = 0.f, aR = 0.f;
        #pragma unroll
        for (int k = 0; k < IN_CH; ++k) {
            aL = fmaf(row[k], W1l[c * IN_CH + k], aL);
            aR = fmaf(row[k], W1r[c * IN_CH + k], aR);
        }
        xl[(size_t)n * HID_CH + c] = aL;
        self1[(size_t)n * HID_CH + c] = aR + b1l[c];
    }
}

// ---------------- Layer-1 scatter: aggr1[dst] += xl[src], deg[dst] += 1
__global__ __launch_bounds__(256) void k_scatter1(
    const int* __restrict__ src, const int* __restrict__ dst,
    const float* __restrict__ xl, float* __restrict__ aggr1,
    float* __restrict__ deg)
{
    int idx = blockIdx.x * blockDim.x + threadIdx.x;
    if (idx >= N_EDGES * 8) return;
    int e = idx >> 3, q = idx & 7;
    int s = src[e], d = dst[e];
    const float4 v = *reinterpret_cast<const float4*>(xl + (size_t)s * HID_CH + q * 4);
    float* p = aggr1 + (size_t)d * HID_CH + q * 4;
    unsafeAtomicAdd(p + 0, v.x);
    unsafeAtomicAdd(p + 1, v.y);
    unsafeAtomicAdd(p + 2, v.z);
    unsafeAtomicAdd(p + 3, v.w);
    if (q == 0) unsafeAtomicAdd(deg + d, 1.0f);
}

// ---------------- Layer-1 finalize + layer-2 node transform (fused)
__global__ __launch_bounds__(256) void k_fin1_xform2(
    const float* __restrict__ aggr1, const float* __restrict__ self1,
    const float* __restrict__ deg,
    const float* __restrict__ W2l, const float* __restrict__ b2l,
    const float* __restrict__ W2r,
    float* __restrict__ hl, float* __restrict__ hself)
{
    int n = blockIdx.x * blockDim.x + threadIdx.x;
    if (n >= N_NODES) return;
    float dinv = 1.0f / fmaxf(deg[n], 1.0f);
    float h[HID_CH];
    float ss = 0.f;
    #pragma unroll
    for (int c = 0; c < HID_CH; c += 4) {
        float4 a = *reinterpret_cast<const float4*>(aggr1 + (size_t)n * HID_CH + c);
        float4 s = *reinterpret_cast<const float4*>(self1 + (size_t)n * HID_CH + c);
        h[c + 0] = fmaf(a.x, dinv, s.x);
        h[c + 1] = fmaf(a.y, dinv, s.y);
        h[c + 2] = fmaf(a.z, dinv, s.z);
        h[c + 3] = fmaf(a.w, dinv, s.w);
        ss += h[c+0]*h[c+0] + h[c+1]*h[c+1] + h[c+2]*h[c+2] + h[c+3]*h[c+3];
    }
    float scale = 1.0f / fmaxf(sqrtf(ss), EPSN);
    #pragma unroll
    for (int c = 0; c < HID_CH; ++c) h[c] = fmaxf(h[c] * scale, 0.f);  // normalize + relu
    #pragma unroll 4
    for (int o = 0; o < OUT_CH; ++o) {
        float aL = 0.f, aR = 0.f;
        #pragma unroll
        for (int k = 0; k < HID_CH; ++k) {
            aL = fmaf(h[k], W2l[o * HID_CH + k], aL);
            aR = fmaf(h[k], W2r[o * HID_CH + k], aR);
        }
        hl[(size_t)n * OUT_CH + o] = aL;
        hself[(size_t)n * OUT_CH + o] = aR + b2l[o];
    }
}

// ---------------- Layer-2 scatter: aggr2[dst] += hl[src]
__global__ __launch_bounds__(256) void k_scatter2(
    const int* __restrict__ src, const int* __restrict__ dst,
    const float* __restrict__ hl, float* __restrict__ aggr2)
{
    int idx = blockIdx.x * blockDim.x + threadIdx.x;
    if (idx >= N_EDGES * 4) return;
    int e = idx >> 2, q = idx & 3;
    int s = src[e], d = dst[e];
    const float4 v = *reinterpret_cast<const float4*>(hl + (size_t)s * OUT_CH + q * 4);
    float* p = aggr2 + (size_t)d * OUT_CH + q * 4;
    unsafeAtomicAdd(p + 0, v.x);
    unsafeAtomicAdd(p + 1, v.y);
    unsafeAtomicAdd(p + 2, v.z);
    unsafeAtomicAdd(p + 3, v.w);
}

// ---------------- Layer-2 finalize: mean + self, normalize, log_softmax
__global__ __launch_bounds__(256) void k_fin2(
    const float* __restrict__ aggr2, const float* __restrict__ hself,
    const float* __restrict__ deg, float* __restrict__ out)
{
    int n = blockIdx.x * blockDim.x + threadIdx.x;
    if (n >= N_NODES) return;
    float dinv = 1.0f / fmaxf(deg[n], 1.0f);
    float v[OUT_CH];
    float ss = 0.f;
    #pragma unroll
    for (int c = 0; c < OUT_CH; c += 4) {
        float4 a = *reinterpret_cast<const float4*>(aggr2 + (size_t)n * OUT_CH + c);
        float4 s = *reinterpret_cast<const float4*>(hself + (size_t)n * OUT_CH + c);
        v[c + 0] = fmaf(a.x, dinv, s.x);
        v[c + 1] = fmaf(a.y, dinv, s.y);
        v[c + 2] = fmaf(a.z, dinv, s.z);
        v[c + 3] = fmaf(a.w, dinv, s.w);
        ss += v[c+0]*v[c+0] + v[c+1]*v[c+1] + v[c+2]*v[c+2] + v[c+3]*v[c+3];
    }
    float scale = 1.0f / fmaxf(sqrtf(ss), EPSN);
    #pragma unroll
    for (int c = 0; c < OUT_CH; ++c) v[c] *= scale;
    // log_softmax over the 16 channels
    float m = v[0];
    #pragma unroll
    for (int c = 1; c < OUT_CH; ++c) m = fmaxf(m, v[c]);
    float sum = 0.f;
    #pragma unroll
    for (int c = 0; c < OUT_CH; ++c) sum += expf(v[c] - m);
    float lse = m + logf(sum);
    #pragma unroll
    for (int c = 0; c < OUT_CH; ++c)
        out[(size_t)n * OUT_CH + c] = v[c] - lse;
}

extern "C" void kernel_launch(void* const* d_in, const int* in_sizes, int n_in,
                              void* d_out, int out_size, void* d_ws, size_t ws_size,
                              hipStream_t stream) {
    const float* x   = (const float*)d_in[0];
    const int*   ei  = (const int*)d_in[1];   // [2, E] int32: row 0 = src, row 1 = dst
    const float* W1l = (const float*)d_in[2];
    const float* b1l = (const float*)d_in[3];
    const float* W1r = (const float*)d_in[4];
    const float* W2l = (const float*)d_in[5];
    const float* b2l = (const float*)d_in[6];
    const float* W2r = (const float*)d_in[7];
    float* out = (float*)d_out;
    float* ws  = (float*)d_ws;

    // workspace layout (floats). Zeroed region first so one memset covers it.
    float* aggr1 = ws;                                   // N*32
    float* deg   = aggr1 + (size_t)N_NODES * HID_CH;     // N
    float* aggr2 = deg + N_NODES;                        // N*16
    float* xl    = aggr2 + (size_t)N_NODES * OUT_CH;     // N*32
    float* self1 = xl + (size_t)N_NODES * HID_CH;        // N*32
    float* hl    = self1 + (size_t)N_NODES * HID_CH;     // N*16
    float* hself = hl + (size_t)N_NODES * OUT_CH;        // N*16

    const int* src = ei;
    const int* dst = ei + N_EDGES;

    hipMemsetAsync(aggr1, 0,
                   (size_t)N_NODES * (HID_CH + 1 + OUT_CH) * sizeof(float),
                   stream);

    dim3 blk(256);
    k_xform1<<<(N_NODES + 255) / 256, blk, 0, stream>>>(x, W1l, b1l, W1r, xl, self1);
    k_scatter1<<<(N_EDGES * 8 + 255) / 256, blk, 0, stream>>>(src, dst, xl, aggr1, deg);
    k_fin1_xform2<<<(N_NODES + 255) / 256, blk, 0, stream>>>(aggr1, self1, deg,
                                                             W2l, b2l, W2r, hl, hself);
    k_scatter2<<<(N_EDGES * 4 + 255) / 256, blk, 0, stream>>>(src, dst, hl, aggr2);
    k_fin2<<<(N_NODES + 255) / 256, blk, 0, stream>>>(aggr2, hself, deg, out);
}

// Round 2
// 367.822 us; speedup vs baseline: 3.1267x; 3.1267x over previous
//
#include <hip/hip_runtime.h>

#define N_NODES 100000
#define N_EDGES 1600000
#define IN_CH 50
#define HID_CH 32
#define OUT_CH 16
#define EPSN 1e-12f

#define SCAN_BS 1024
#define SCAN_NB ((N_NODES + SCAN_BS - 1) / SCAN_BS)   // 98

// ---------------- degree histogram (int atomics, 1.6M)
__global__ __launch_bounds__(256) void k_deg(
    const int* __restrict__ dst, int* __restrict__ deg)
{
    int e = blockIdx.x * blockDim.x + threadIdx.x;
    if (e >= N_EDGES) return;
    atomicAdd(&deg[dst[e]], 1);
}

// ---------------- block-level exclusive scan of deg
__global__ __launch_bounds__(SCAN_BS) void k_scan_block(
    const int* __restrict__ deg, int* __restrict__ offs, int* __restrict__ bsum)
{
    __shared__ int buf[SCAN_BS];
    int tid = threadIdx.x;
    int gid = blockIdx.x * SCAN_BS + tid;
    int v = (gid < N_NODES) ? deg[gid] : 0;
    buf[tid] = v;
    __syncthreads();
    for (int off = 1; off < SCAN_BS; off <<= 1) {
        int t = (tid >= off) ? buf[tid - off] : 0;
        __syncthreads();
        buf[tid] += t;
        __syncthreads();
    }
    if (gid < N_NODES) offs[gid] = buf[tid] - v;          // exclusive
    if (tid == SCAN_BS - 1) bsum[blockIdx.x] = buf[tid];  // block total
}

// ---------------- scan of block sums (single block)
__global__ __launch_bounds__(128) void k_scan_top(
    const int* __restrict__ bsum, int* __restrict__ bexc)
{
    __shared__ int buf[128];
    int tid = threadIdx.x;
    int v = (tid < SCAN_NB) ? bsum[tid] : 0;
    buf[tid] = v;
    __syncthreads();
    for (int off = 1; off < 128; off <<= 1) {
        int t = (tid >= off) ? buf[tid - off] : 0;
        __syncthreads();
        buf[tid] += t;
        __syncthreads();
    }
    if (tid < SCAN_NB) bexc[tid] = buf[tid] - v;
}

// ---------------- add block offsets; init cursor copy
__global__ __launch_bounds__(SCAN_BS) void k_scan_add(
    int* __restrict__ offs, const int* __restrict__ bexc, int* __restrict__ cursor)
{
    int gid = blockIdx.x * SCAN_BS + threadIdx.x;
    if (gid >= N_NODES) return;
    int o = offs[gid] + bexc[blockIdx.x];
    offs[gid] = o;
    cursor[gid] = o;
}

// ---------------- fill CSR: csr_src[slot] = src[e], grouped by dst
__global__ __launch_bounds__(256) void k_fill(
    const int* __restrict__ src, const int* __restrict__ dst,
    int* __restrict__ cursor, int* __restrict__ csr_src)
{
    int e = blockIdx.x * blockDim.x + threadIdx.x;
    if (e >= N_EDGES) return;
    int d = dst[e];
    int pos = atomicAdd(&cursor[d], 1);
    csr_src[pos] = src[e];
}

// ---------------- layer-1 node transform: xl = x@W1l.T, self1 = x@W1r.T + b1l
__global__ __launch_bounds__(256) void k_xform1(
    const float* __restrict__ x, const float* __restrict__ W1l,
    const float* __restrict__ b1l, const float* __restrict__ W1r,
    float* __restrict__ xl, float* __restrict__ self1)
{
    int n = blockIdx.x * blockDim.x + threadIdx.x;
    if (n >= N_NODES) return;
    float row[IN_CH];
    #pragma unroll
    for (int k = 0; k < IN_CH; ++k) row[k] = x[(size_t)n * IN_CH + k];
    #pragma unroll 4
    for (int c = 0; c < HID_CH; ++c) {
        float aL = 0.f, aR = 0.f;
        #pragma unroll
        for (int k = 0; k < IN_CH; ++k) {
            aL = fmaf(row[k], W1l[c * IN_CH + k], aL);
            aR = fmaf(row[k], W1r[c * IN_CH + k], aR);
        }
        xl[(size_t)n * HID_CH + c] = aL;
        self1[(size_t)n * HID_CH + c] = aR + b1l[c];
    }
}

// ---------------- layer-1 gather-aggregate + mean + self + L2norm + relu -> h
// 16 threads per node, 2 channels per thread (float2). No atomics.
__global__ __launch_bounds__(256) void k_aggr1(
    const int* __restrict__ offs, const int* __restrict__ deg,
    const int* __restrict__ csr_src,
    const float* __restrict__ xl, const float* __restrict__ self1,
    float* __restrict__ h)
{
    int gid = blockIdx.x * blockDim.x + threadIdx.x;
    int n = gid >> 4;
    int t = gid & 15;
    if (n >= N_NODES) return;
    int beg = offs[n];
    int dg = deg[n];
    float ax = 0.f, ay = 0.f, bx = 0.f, by = 0.f;
    int i = 0;
    for (; i + 1 < dg; i += 2) {
        int s0 = csr_src[beg + i];
        int s1 = csr_src[beg + i + 1];
        float2 v0 = *reinterpret_cast<const float2*>(xl + (size_t)s0 * HID_CH + t * 2);
        float2 v1 = *reinterpret_cast<const float2*>(xl + (size_t)s1 * HID_CH + t * 2);
        ax += v0.x; ay += v0.y; bx += v1.x; by += v1.y;
    }
    if (i < dg) {
        int s0 = csr_src[beg + i];
        float2 v0 = *reinterpret_cast<const float2*>(xl + (size_t)s0 * HID_CH + t * 2);
        ax += v0.x; ay += v0.y;
    }
    float invd = 1.0f / (float)max(dg, 1);
    float2 sf = *reinterpret_cast<const float2*>(self1 + (size_t)n * HID_CH + t * 2);
    float h0 = fmaf(ax + bx, invd, sf.x);
    float h1 = fmaf(ay + by, invd, sf.y);
    float ss = h0 * h0 + h1 * h1;
    ss += __shfl_xor(ss, 1);
    ss += __shfl_xor(ss, 2);
    ss += __shfl_xor(ss, 4);
    ss += __shfl_xor(ss, 8);
    float scale = 1.0f / fmaxf(sqrtf(ss), EPSN);
    float2 ho;
    ho.x = fmaxf(h0 * scale, 0.f);
    ho.y = fmaxf(h1 * scale, 0.f);
    *reinterpret_cast<float2*>(h + (size_t)n * HID_CH + t * 2) = ho;
}

// ---------------- layer-2 node transform: hl = h@W2l.T, hself = h@W2r.T + b2l
__global__ __launch_bounds__(256) void k_xform2(
    const float* __restrict__ h, const float* __restrict__ W2l,
    const float* __restrict__ b2l, const float* __restrict__ W2r,
    float* __restrict__ hl, float* __restrict__ hself)
{
    int n = blockIdx.x * blockDim.x + threadIdx.x;
    if (n >= N_NODES) return;
    float row[HID_CH];
    #pragma unroll
    for (int k = 0; k < HID_CH; ++k) row[k] = h[(size_t)n * HID_CH + k];
    #pragma unroll 4
    for (int o = 0; o < OUT_CH; ++o) {
        float aL = 0.f, aR = 0.f;
        #pragma unroll
        for (int k = 0; k < HID_CH; ++k) {
            aL = fmaf(row[k], W2l[o * HID_CH + k], aL);
            aR = fmaf(row[k], W2r[o * HID_CH + k], aR);
        }
        hl[(size_t)n * OUT_CH + o] = aL;
        hself[(size_t)n * OUT_CH + o] = aR + b2l[o];
    }
}

// ---------------- layer-2 gather-aggregate + mean + self + L2norm + log_softmax
// 16 threads per node, 1 channel per thread.
__global__ __launch_bounds__(256) void k_aggr2_fin(
    const int* __restrict__ offs, const int* __restrict__ deg,
    const int* __restrict__ csr_src,
    const float* __restrict__ hl, const float* __restrict__ hself,
    float* __restrict__ out)
{
    int gid = blockIdx.x * blockDim.x + threadIdx.x;
    int n = gid >> 4;
    int t = gid & 15;
    if (n >= N_NODES) return;
    int beg = offs[n];
    int dg = deg[n];
    float a0 = 0.f, a1 = 0.f;
    int i = 0;
    for (; i + 1 < dg; i += 2) {
        int s0 = csr_src[beg + i];
        int s1 = csr_src[beg + i + 1];
        a0 += hl[(size_t)s0 * OUT_CH + t];
        a1 += hl[(size_t)s1 * OUT_CH + t];
    }
    if (i < dg) a0 += hl[(size_t)csr_src[beg + i] * OUT_CH + t];
    float invd = 1.0f / (float)max(dg, 1);
    float v = fmaf(a0 + a1, invd, hself[(size_t)n * OUT_CH + t]);
    float ss = v * v;
    ss += __shfl_xor(ss, 1);
    ss += __shfl_xor(ss, 2);
    ss += __shfl_xor(ss, 4);
    ss += __shfl_xor(ss, 8);
    float scale = 1.0f / fmaxf(sqrtf(ss), EPSN);
    v *= scale;
    float m = v;
    m = fmaxf(m, __shfl_xor(m, 1));
    m = fmaxf(m, __shfl_xor(m, 2));
    m = fmaxf(m, __shfl_xor(m, 4));
    m = fmaxf(m, __shfl_xor(m, 8));
    float ex = expf(v - m);
    float sum = ex;
    sum += __shfl_xor(sum, 1);
    sum += __shfl_xor(sum, 2);
    sum += __shfl_xor(sum, 4);
    sum += __shfl_xor(sum, 8);
    float lse = m + logf(sum);
    out[(size_t)n * OUT_CH + t] = v - lse;
}

extern "C" void kernel_launch(void* const* d_in, const int* in_sizes, int n_in,
                              void* d_out, int out_size, void* d_ws, size_t ws_size,
                              hipStream_t stream) {
    const float* x   = (const float*)d_in[0];
    const int*   ei  = (const int*)d_in[1];   // [2, E] int32
    const float* W1l = (const float*)d_in[2];
    const float* b1l = (const float*)d_in[3];
    const float* W1r = (const float*)d_in[4];
    const float* W2l = (const float*)d_in[5];
    const float* b2l = (const float*)d_in[6];
    const float* W2r = (const float*)d_in[7];
    float* out = (float*)d_out;

    const int* src = ei;
    const int* dst = ei + N_EDGES;

    // workspace layout
    char* p = (char*)d_ws;
    float* xl    = (float*)p; p += (size_t)N_NODES * HID_CH * 4;  // 12.8 MB
    float* self1 = (float*)p; p += (size_t)N_NODES * HID_CH * 4;  // 12.8 MB
    float* h     = (float*)p; p += (size_t)N_NODES * HID_CH * 4;  // 12.8 MB
    float* hl    = (float*)p; p += (size_t)N_NODES * OUT_CH * 4;  //  6.4 MB
    float* hself = (float*)p; p += (size_t)N_NODES * OUT_CH * 4;  //  6.4 MB
    int*   deg   = (int*)p;   p += (size_t)N_NODES * 4;
    int*   offs  = (int*)p;   p += (size_t)N_NODES * 4;
    int*   cursor= (int*)p;   p += (size_t)N_NODES * 4;
    int*   bsum  = (int*)p;   p += 128 * 4;
    int*   bexc  = (int*)p;   p += 128 * 4;
    int*   csr   = (int*)p;   p += (size_t)N_EDGES * 4;           //  6.4 MB

    hipMemsetAsync(deg, 0, (size_t)N_NODES * 4, stream);

    const int EB = (N_EDGES + 255) / 256;
    const int NB16 = (N_NODES * 16 + 255) / 256;
    const int NBN = (N_NODES + 255) / 256;

    // CSR build
    k_deg<<<EB, 256, 0, stream>>>(dst, deg);
    k_scan_block<<<SCAN_NB, SCAN_BS, 0, stream>>>(deg, offs, bsum);
    k_scan_top<<<1, 128, 0, stream>>>(bsum, bexc);
    k_scan_add<<<SCAN_NB, SCAN_BS, 0, stream>>>(offs, bexc, cursor);
    k_fill<<<EB, 256, 0, stream>>>(src, dst, cursor, csr);

    // layer 1
    k_xform1<<<NBN, 256, 0, stream>>>(x, W1l, b1l, W1r, xl, self1);
    k_aggr1<<<NB16, 256, 0, stream>>>(offs, deg, csr, xl, self1, h);

    // layer 2
    k_xform2<<<NBN, 256, 0, stream>>>(h, W2l, b2l, W2r, hl, hself);
    k_aggr2_fin<<<NB16, 256, 0, stream>>>(offs, deg, csr, hl, hself, out);
}